// Round 5
// baseline (1286.063 us; speedup 1.0000x reference)
//
#include <hip/hip_runtime.h>
#include <hip/hip_cooperative_groups.h>
#include <cstdint>

namespace cg = cooperative_groups;

#define NN 100000
#define NE 1600000
#define DD 128
#define NB 250            // node buckets
#define BSZ 400           // nodes per bucket  (NB*BSZ == NN)
#define GB 1024           // bcp stride (max grid blocks)
#define WTS 136
#define NTILES ((NN + 63) / 64)

typedef unsigned int uint;
typedef unsigned short ushort;
typedef unsigned long long u64;

typedef __attribute__((ext_vector_type(8))) short short8;   // 8 bf16 (4 VGPRs)
typedef __attribute__((ext_vector_type(4))) float floatx4;  // MFMA acc

struct FusedP {
    const float* feat; const int* srcp; const int* dstp; const float* ew;
    const float* W1; const float* b1; const float* a1;
    const float* W2; const float* b2; const float* a2;
    ushort* wt1; ushort* wt2;
    uint* bcp; uint* bbase; uint* bcur;
    float* dis; int* hist; int* rowstart;
    int2* etmp; int2* edges;
    ushort* hb; ushort* x1b; float* out;
};

// fp32 -> bf16 bits, round-to-nearest-even
__device__ inline uint f2bf(float f) {
    uint u = __float_as_uint(f);
    return (u + 0x7fffu + ((u >> 16) & 1u)) >> 16;
}

// ---------------- GEMM phase: HB[r,:] = bf16( (X[r,:] @ W) * dis[r] ) ----------------
// W pre-converted/transposed (wt*, bf16 [n][k]); staged into padded LDS
// (WTS=136 -> 16B-aligned ds_read_b128, <=2-way bank aliasing = free).
// Layouts (m89/m91): A: m=lane&15, k=(lane>>4)*8+j; B: n=lane&15, same k;
// D: col=lane&15, row=(lane>>4)*4+reg.
template <bool AF32>
__device__ __forceinline__ void gemm_phase(const void* Xv, const ushort* Wtg,
                                           const float* dis, ushort* HB,
                                           char* smem, int tid) {
    ushort* Wt = (ushort*)smem;
#pragma unroll
    for (int u = 0; u < 8; ++u) {
        int unit = tid + u * 256;
        int n = unit >> 4, c = unit & 15;
        *(short8*)&Wt[n * WTS + c * 8] = *(const short8*)(Wtg + n * DD + c * 8);
    }
    __syncthreads();

    int lane = tid & 63;
    int wave = tid >> 6;
    int q = lane >> 4, l16 = lane & 15;

    for (int tile = blockIdx.x; tile < NTILES; tile += gridDim.x) {
        int row0 = tile * 64 + wave * 16;
        int arow = row0 + l16;
        if (arow >= NN) arow = NN - 1;
        short8 afr[4];
        if (AF32) {
            const float* xr = (const float*)Xv + (size_t)arow * DD + q * 8;
#pragma unroll
            for (int ks = 0; ks < 4; ++ks) {
                float4 f0 = *(const float4*)(xr + ks * 32);
                float4 f1 = *(const float4*)(xr + ks * 32 + 4);
                uint4 u;
                u.x = f2bf(f0.x) | (f2bf(f0.y) << 16);
                u.y = f2bf(f0.z) | (f2bf(f0.w) << 16);
                u.z = f2bf(f1.x) | (f2bf(f1.y) << 16);
                u.w = f2bf(f1.z) | (f2bf(f1.w) << 16);
                afr[ks] = __builtin_bit_cast(short8, u);
            }
        } else {
            const ushort* xr = (const ushort*)Xv + (size_t)arow * DD + q * 8;
#pragma unroll
            for (int ks = 0; ks < 4; ++ks)
                afr[ks] = *(const short8*)(xr + ks * 32);
        }

        floatx4 acc[8];
#pragma unroll
        for (int ct = 0; ct < 8; ++ct) acc[ct] = (floatx4)(0.0f);

#pragma unroll
        for (int ct = 0; ct < 8; ++ct) {
            const ushort* wp = &Wt[(ct * 16 + l16) * WTS + q * 8];
#pragma unroll
            for (int ks = 0; ks < 4; ++ks) {
                short8 bfr = *(const short8*)(wp + ks * 32);
                acc[ct] = __builtin_amdgcn_mfma_f32_16x16x32_bf16(afr[ks], bfr, acc[ct], 0, 0, 0);
            }
        }

#pragma unroll
        for (int reg = 0; reg < 4; ++reg) {
            int r = row0 + q * 4 + reg;
            if (r < NN) {
                float ds = dis[r];
                ushort* orow = HB + (size_t)r * DD + l16;
#pragma unroll
                for (int ct = 0; ct < 8; ++ct)
                    orow[ct * 16] = (ushort)f2bf(acc[ct][reg] * ds);
            }
        }
    }
    __syncthreads();
}

// ---------------- gather phase: fused gather + self-loop + bias + PReLU ----------------
// Wave per 2 nodes interleaved (32 gathers in flight). Edge records at wave-
// uniform addresses -> scalar loads. Tail-dead gathers clamp to row 0, norm 0.
// Overread past edge-list end (<=120 B) lands in adjacent hb region (valid).
template <bool BF16OUT>
__device__ __forceinline__ void gather_phase(const ushort* hb, const int2* edges,
                                             const int* rowstart, const int* hist,
                                             const float* dis, const float* bv,
                                             const float* av, void* xout, int tid) {
    int wid = __builtin_amdgcn_readfirstlane(tid >> 6);
    int lane = tid & 63;
    uint lane4 = (uint)lane * 4u;
    const char* hbase = (const char*)hb;

    for (int g = blockIdx.x; g < NN / 8; g += gridDim.x) {
        int nodeA = g * 8 + wid * 2;
        int nodeB = nodeA + 1;

        int rsA  = rowstart[nodeA];
        int rsB  = rowstart[nodeB];
        int cntA = hist[nodeA];
        int cntB = hist[nodeB];
        float dsA = dis[nodeA];
        float dsB = dis[nodeB];
        const int2* epA = edges + rsA;
        const int2* epB = edges + rsB;

        uint suA = *(const uint*)(hbase + ((size_t)(uint)nodeA << 8) + lane4);
        uint suB = *(const uint*)(hbase + ((size_t)(uint)nodeB << 8) + lane4);
        float2 a0, a1, a2, a3, b0, b1, b2, b3;
        a0.x = __uint_as_float(suA << 16) * dsA;
        a0.y = __uint_as_float(suA & 0xffff0000u) * dsA;
        b0.x = __uint_as_float(suB << 16) * dsB;
        b0.y = __uint_as_float(suB & 0xffff0000u) * dsB;
        a1 = make_float2(0.f, 0.f); a2 = a1; a3 = a1;
        b1 = a1; b2 = a1; b3 = a1;

        int nbA = (cntA + 15) >> 4;
        int nbB = (cntB + 15) >> 4;
        int nb = nbA > nbB ? nbA : nbB;

        for (int t = 0; t < nb; ++t) {
            int remA = cntA - t * 16;
            int remB = cntB - t * 16;
            int2 eA[16], eB[16];
#pragma unroll
            for (int k = 0; k < 16; ++k) eA[k] = epA[t * 16 + k];
#pragma unroll
            for (int k = 0; k < 16; ++k) eB[k] = epB[t * 16 + k];

            uint gA[16], gB[16];
            float nA[16], nB[16];
#pragma unroll
            for (int k = 0; k < 16; ++k) {
                bool live = k < remA;
                uint s = live ? (uint)eA[k].x : 0u;
                nA[k] = live ? __int_as_float(eA[k].y) : 0.0f;
                gA[k] = *(const uint*)(hbase + ((size_t)s << 8) + lane4);
            }
#pragma unroll
            for (int k = 0; k < 16; ++k) {
                bool live = k < remB;
                uint s = live ? (uint)eB[k].x : 0u;
                nB[k] = live ? __int_as_float(eB[k].y) : 0.0f;
                gB[k] = *(const uint*)(hbase + ((size_t)s << 8) + lane4);
            }
#pragma unroll
            for (int k = 0; k < 16; ++k) {
                float2* ac = (k & 3) == 0 ? &a0 : (k & 3) == 1 ? &a1 : (k & 3) == 2 ? &a2 : &a3;
                ac->x += __uint_as_float(gA[k] << 16) * nA[k];
                ac->y += __uint_as_float(gA[k] & 0xffff0000u) * nA[k];
            }
#pragma unroll
            for (int k = 0; k < 16; ++k) {
                float2* ac = (k & 3) == 0 ? &b0 : (k & 3) == 1 ? &b1 : (k & 3) == 2 ? &b2 : &b3;
                ac->x += __uint_as_float(gB[k] << 16) * nB[k];
                ac->y += __uint_as_float(gB[k] & 0xffff0000u) * nB[k];
            }
        }

        float2 bb = ((const float2*)bv)[lane];
        float2 aa = ((const float2*)av)[lane];
        float rA0 = a0.x + a1.x + a2.x + a3.x + bb.x;
        float rA1 = a0.y + a1.y + a2.y + a3.y + bb.y;
        float rB0 = b0.x + b1.x + b2.x + b3.x + bb.x;
        float rB1 = b0.y + b1.y + b2.y + b3.y + bb.y;
        rA0 = rA0 >= 0.f ? rA0 : aa.x * rA0;
        rA1 = rA1 >= 0.f ? rA1 : aa.y * rA1;
        rB0 = rB0 >= 0.f ? rB0 : aa.x * rB0;
        rB1 = rB1 >= 0.f ? rB1 : aa.y * rB1;
        if (BF16OUT) {
            ((uint*)xout)[(size_t)nodeA * 64 + lane] = f2bf(rA0) | (f2bf(rA1) << 16);
            ((uint*)xout)[(size_t)nodeB * 64 + lane] = f2bf(rB0) | (f2bf(rB1) << 16);
        } else {
            float2 oA; oA.x = rA0; oA.y = rA1;
            float2 oB; oB.x = rB0; oB.y = rB1;
            ((float2*)xout)[(size_t)nodeA * 64 + lane] = oA;
            ((float2*)xout)[(size_t)nodeB * 64 + lane] = oB;
        }
    }
}

// ---------------- the whole pipeline, one cooperative kernel ----------------
__global__ __launch_bounds__(256, 4) void fused_all(FusedP p) {
    __shared__ __align__(16) char smem[DD * WTS * 2];   // 34816 B union
    int tid = threadIdx.x;
    cg::grid_group grid = cg::this_grid();

    // ---- P0: prep_w (bf16 transpose of W1/W2) + bucket histogram partials ----
    for (int i = blockIdx.x * 256 + tid; i < DD * DD; i += gridDim.x * 256) {
        int k = i >> 7, n = i & 127;
        p.wt1[n * DD + k] = (ushort)f2bf(p.W1[i]);
        p.wt2[n * DD + k] = (ushort)f2bf(p.W2[i]);
    }
    {
        uint* h = (uint*)smem;
        if (tid < NB) h[tid] = 0u;
        __syncthreads();
        for (int e = blockIdx.x * 256 + tid; e < NE; e += gridDim.x * 256)
            atomicAdd(&h[(uint)p.dstp[e] / BSZ], 1u);
        __syncthreads();
        if (tid < NB) p.bcp[(size_t)tid * GB + blockIdx.x] = h[tid];
    }
    __threadfence();
    grid.sync();

    // ---- P1: reduce partials + exclusive bucket prefix (block 0) ----
    if (blockIdx.x == 0) {
        uint* cnt = (uint*)smem;
        if (tid < NB) {
            const uint4* q4 = (const uint4*)(p.bcp + (size_t)tid * GB);
            uint s = 0;
            int nj = gridDim.x >> 2;           // gridDim multiple of 256
            for (int j = 0; j < nj; ++j) { uint4 v = q4[j]; s += v.x + v.y + v.z + v.w; }
            cnt[tid] = s;
        }
        __syncthreads();
        if (tid < 64) {
            uint v[4], s = 0;
#pragma unroll
            for (int k = 0; k < 4; ++k) {
                int i = tid * 4 + k;
                v[k] = (i < NB) ? cnt[i] : 0u;
                s += v[k];
            }
            uint inc = s;
#pragma unroll
            for (int d = 1; d < 64; d <<= 1) {
                uint t = __shfl_up(inc, (unsigned)d, 64);
                if (tid >= d) inc += t;
            }
            uint run = inc - s;
#pragma unroll
            for (int k = 0; k < 4; ++k) {
                int i = tid * 4 + k;
                if (i < NB) { p.bbase[i] = run; p.bcur[i] = run; run += v[k]; }
            }
            if (tid == 63) p.bbase[NB] = run;   // == NE
        }
    }
    __threadfence();
    grid.sync();

    // ---- P2: block-aggregated append into bucket regions ----
    {
        uint* h = (uint*)smem;
        uint* res = (uint*)smem + 256;
        for (int e0b = blockIdx.x * 4096; e0b < NE; e0b += gridDim.x * 4096) {
            if (tid < NB) h[tid] = 0u;
            __syncthreads();
            int e0 = e0b + tid;
            uint rank[16], bkt[16];
#pragma unroll
            for (int k = 0; k < 16; ++k) {
                int e = e0 + 256 * k;
                if (e < NE) {
                    uint bk = (uint)p.dstp[e] / BSZ;
                    bkt[k] = bk;
                    rank[k] = atomicAdd(&h[bk], 1u);
                } else bkt[k] = 0xffffffffu;
            }
            __syncthreads();
            if (tid < NB) res[tid] = h[tid] ? atomicAdd(&p.bcur[tid], h[tid]) : 0u;
            __syncthreads();
#pragma unroll
            for (int k = 0; k < 16; ++k) {
                if (bkt[k] != 0xffffffffu) {
                    int e = e0 + 256 * k;
                    uint dl = (uint)p.dstp[e] - bkt[k] * BSZ;
                    uint wq = (uint)(p.ew[e] * 8388608.0f);
                    if (wq > 8388607u) wq = 8388607u;
                    p.etmp[res[bkt[k]] + rank[k]] = make_int2(p.srcp[e], (int)((dl << 23) | wq));
                }
            }
            __syncthreads();
        }
    }
    __threadfence();
    grid.sync();

    // ---- P3: per-bucket deg->dis, per-node scan -> rowstart, exact placement ----
    {
        u64*   wc   = (u64*)smem;
        uint*  curq = (uint*)(smem + BSZ * 8);
        float* disl = (float*)(smem + BSZ * 8 + BSZ * 4);
        for (int b = blockIdx.x; b < NB; b += gridDim.x) {
            int n0 = b * BSZ;
            for (int i = tid; i < BSZ; i += 256) wc[i] = 0ull;
            __syncthreads();
            uint base = p.bbase[b], end = p.bbase[b + 1];
            for (uint i = base + tid; i < end; i += 256) {
                uint y = (uint)p.etmp[i].y;
                atomicAdd(&wc[y >> 23], ((u64)1 << 40) | (u64)(y & 0x7fffffu));
            }
            __syncthreads();
            if (tid < 64) {
                uint v[7], s = 0;
#pragma unroll
                for (int k = 0; k < 7; ++k) {
                    int i = tid * 7 + k;
                    v[k] = (i < BSZ) ? (uint)(wc[i] >> 40) : 0u;
                    s += v[k];
                }
                uint inc = s;
#pragma unroll
                for (int d = 1; d < 64; d <<= 1) {
                    uint t = __shfl_up(inc, (unsigned)d, 64);
                    if (tid >= d) inc += t;
                }
                uint run = inc - s;
#pragma unroll
                for (int k = 0; k < 7; ++k) {
                    int i = tid * 7 + k;
                    if (i < BSZ) { curq[i] = run; run += v[k]; }
                }
            }
            __syncthreads();
            for (int i = tid; i < BSZ; i += 256) {
                u64 v = wc[i];
                float wsum = (float)(v & 0xffffffffffull) * (1.0f / 8388608.0f);
                float dsv = rsqrtf(1.0f + wsum);
                disl[i] = dsv;
                p.dis[n0 + i] = dsv;
                p.hist[n0 + i] = (int)(v >> 40);
                p.rowstart[n0 + i] = (int)(base + curq[i]);
            }
            __syncthreads();
            for (uint i = base + tid; i < end; i += 256) {
                int2 e = p.etmp[i];
                uint y = (uint)e.y;
                uint dl = y >> 23;
                float wv = (float)(y & 0x7fffffu) * (1.0f / 8388608.0f);
                uint pos = atomicAdd(&curq[dl], 1u);
                p.edges[base + pos] = make_int2(e.x, __float_as_int(wv * disl[dl]));
            }
            __syncthreads();
        }
    }
    __threadfence();
    grid.sync();

    // ---- P4: layer-1 GEMM ----
    gemm_phase<true>(p.feat, p.wt1, p.dis, p.hb, smem, tid);
    __threadfence();
    grid.sync();

    // ---- P5: layer-1 gather/finalize -> x1b (bf16) ----
    gather_phase<true>(p.hb, p.edges, p.rowstart, p.hist, p.dis, p.b1, p.a1, p.x1b, tid);
    __threadfence();
    grid.sync();

    // ---- P6: layer-2 GEMM ----
    gemm_phase<false>(p.x1b, p.wt2, p.dis, p.hb, smem, tid);
    __threadfence();
    grid.sync();

    // ---- P7: layer-2 gather/finalize -> out (f32) ----
    gather_phase<false>(p.hb, p.edges, p.rowstart, p.hist, p.dis, p.b2, p.a2, p.out, tid);
}

extern "C" void kernel_launch(void* const* d_in, const int* in_sizes, int n_in,
                              void* d_out, int out_size, void* d_ws, size_t ws_size,
                              hipStream_t stream) {
    // workspace carve (bytes), all 16B-aligned
    char* wsb = (char*)d_ws;
    size_t off = 0;
    uint* bcp     = (uint*)(wsb + off); off += 4ull * NB * GB;       // 1 MB partials
    ushort* wt1   = (ushort*)(wsb + off); off += 2ull * DD * DD;     // 32 KB
    ushort* wt2   = (ushort*)(wsb + off); off += 2ull * DD * DD;     // 32 KB
    uint* bbase   = (uint*)(wsb + off); off += 4096;                 // NB+1
    uint* bcur    = (uint*)(wsb + off); off += 4096;                 // NB
    float* dis    = (float*)(wsb + off); off += 4ull * NN;
    int* hist     = (int*)(wsb + off); off += 4ull * NN;
    int* rowstart = (int*)(wsb + off); off += 4ull * NN;
    int2* etmp    = (int2*)(wsb + off); off += 8ull * NE;
    int2* edges   = (int2*)(wsb + off); off += 8ull * NE;            // followed by hb: gather overread safe
    ushort* hb    = (ushort*)(wsb + off); off += 2ull * NN * DD;
    ushort* x1b   = (ushort*)(wsb + off); off += 2ull * NN * DD;

    FusedP p;
    p.feat = (const float*)d_in[0];
    p.srcp = (const int*)d_in[1];
    p.dstp = (const int*)d_in[1] + NE;
    p.ew   = (const float*)d_in[2];
    p.W1 = (const float*)d_in[3]; p.b1 = (const float*)d_in[4]; p.a1 = (const float*)d_in[5];
    p.W2 = (const float*)d_in[6]; p.b2 = (const float*)d_in[7]; p.a2 = (const float*)d_in[8];
    p.wt1 = wt1; p.wt2 = wt2;
    p.bcp = bcp; p.bbase = bbase; p.bcur = bcur;
    p.dis = dis; p.hist = hist; p.rowstart = rowstart;
    p.etmp = etmp; p.edges = edges;
    p.hb = hb; p.x1b = x1b;
    p.out = (float*)d_out;

    static int gblocks = 0;
    if (gblocks == 0) {
        int nb = 0;
        hipOccupancyMaxActiveBlocksPerMultiprocessor(&nb, fused_all, 256, 0);
        int g = nb * 256;                 // 256 CUs
        if (g > GB) g = GB;
        if (g < 256) g = 256;             // need >= NB blocks for P3
        gblocks = g;
    }

    void* kp[] = { (void*)&p };
    hipLaunchCooperativeKernel((const void*)fused_all, dim3(gblocks), dim3(256),
                               kp, 0, stream);
}

// Round 6
// 343.926 us; speedup vs baseline: 3.7394x; 3.7394x over previous
//
#include <hip/hip_runtime.h>
#include <cstdint>

#define NN 100000
#define NE 1600000
#define DD 128
#define NB 250            // node buckets
#define BSZ 400           // nodes per bucket  (NB*BSZ == NN)
#define NHB ((NE + 8191) / 8192)   // bucket_hist blocks = 196 (divisible by 4)

typedef unsigned int uint;
typedef unsigned short ushort;
typedef unsigned long long u64;

typedef __attribute__((ext_vector_type(8))) short short8;   // 8 bf16 (4 VGPRs)
typedef __attribute__((ext_vector_type(4))) float floatx4;  // MFMA acc

// fp32 -> bf16 bits, round-to-nearest-even
__device__ inline uint f2bf(float f) {
    uint u = __float_as_uint(f);
    return (u + 0x7fffu + ((u >> 16) & 1u)) >> 16;
}

// ---------------- Pass 1: bucket histogram partials + W prep (fused) ----------------
// bcp layout: TRANSPOSED, bcp[bucket][block] -> contiguous uint4 reduce in pass 2.
// prep_w folded in: first 16384 threads also emit bf16-transposed W1/W2.
__global__ __launch_bounds__(256) void bucket_hist(const int* __restrict__ dst,
                                                   uint* __restrict__ bcp,
                                                   const float* __restrict__ W1,
                                                   const float* __restrict__ W2,
                                                   ushort* __restrict__ Wt1,
                                                   ushort* __restrict__ Wt2) {
    __shared__ uint h[NB];
    int tid = threadIdx.x;
    int gi = blockIdx.x * 256 + tid;
    if (gi < DD * DD) {                       // one-shot weight transpose+convert
        int k = gi >> 7, n = gi & 127;        // W[k][n] row-major
        Wt1[n * DD + k] = (ushort)f2bf(W1[gi]);
        Wt2[n * DD + k] = (ushort)f2bf(W2[gi]);
    }
    if (tid < NB) h[tid] = 0u;
    __syncthreads();
    int e0 = blockIdx.x * 8192 + tid;
#pragma unroll
    for (int k = 0; k < 32; ++k) {
        int e = e0 + 256 * k;
        if (e < NE) atomicAdd(&h[(uint)dst[e] / BSZ], 1u);
    }
    __syncthreads();
    if (tid < NB) bcp[(size_t)tid * NHB + blockIdx.x] = h[tid];
}

// ---------------- Pass 2: reduce partials + exclusive bucket prefix ----------------
__global__ __launch_bounds__(256) void bucket_prefix(const uint* __restrict__ bcp,
                                                     uint* __restrict__ bbase,
                                                     uint* __restrict__ bcur) {
    __shared__ uint cnt[NB];
    int tid = threadIdx.x;
    if (tid < NB) {
        const uint4* p = (const uint4*)(bcp + (size_t)tid * NHB);
        uint s = 0;
#pragma unroll 7
        for (int j = 0; j < NHB / 4; ++j) {     // 49 vec4 loads, contiguous
            uint4 v = p[j];
            s += v.x + v.y + v.z + v.w;
        }
        cnt[tid] = s;
    }
    __syncthreads();
    int lane = tid;
    if (lane < 64) {
        uint v[4], s = 0;
#pragma unroll
        for (int k = 0; k < 4; ++k) {
            int i = lane * 4 + k;
            v[k] = (i < NB) ? cnt[i] : 0u;
            s += v[k];
        }
        uint inc = s;
#pragma unroll
        for (int d = 1; d < 64; d <<= 1) {
            uint t = __shfl_up(inc, (unsigned)d, 64);
            if (lane >= d) inc += t;
        }
        uint run = inc - s;      // exclusive chunk base
#pragma unroll
        for (int k = 0; k < 4; ++k) {
            int i = lane * 4 + k;
            if (i < NB) { bbase[i] = run; bcur[i] = run; run += v[k]; }
        }
        if (lane == 63) bbase[NB] = run;   // == NE
    }
}

// ---------------- Pass 3: block-aggregated append into bucket regions ----------------
// payload: {src, (dstLocal<<23) | wq23}
__global__ __launch_bounds__(256) void bucket_append(const int* __restrict__ src,
                                                     const int* __restrict__ dst,
                                                     const float* __restrict__ w,
                                                     uint* __restrict__ bcur,
                                                     int2* __restrict__ etmp) {
    __shared__ uint h[NB];
    __shared__ uint res[NB];
    int tid = threadIdx.x;
    if (tid < NB) h[tid] = 0u;
    __syncthreads();
    int e0 = blockIdx.x * 4096 + tid;
    uint rank[16], bkt[16];
#pragma unroll
    for (int k = 0; k < 16; ++k) {
        int e = e0 + 256 * k;
        if (e < NE) {
            uint b = (uint)dst[e] / BSZ;
            bkt[k] = b;
            rank[k] = atomicAdd(&h[b], 1u);
        } else bkt[k] = 0xffffffffu;
    }
    __syncthreads();
    if (tid < NB) res[tid] = h[tid] ? atomicAdd(&bcur[tid], h[tid]) : 0u;
    __syncthreads();
#pragma unroll
    for (int k = 0; k < 16; ++k) {
        if (bkt[k] != 0xffffffffu) {
            int e = e0 + 256 * k;
            uint dl = (uint)dst[e] - bkt[k] * BSZ;
            uint wq = (uint)(w[e] * 8388608.0f);
            if (wq > 8388607u) wq = 8388607u;
            etmp[res[bkt[k]] + rank[k]] = make_int2(src[e], (int)((dl << 23) | wq));
        }
    }
}

// ---------------- Pass 4: per-bucket deg->dis, scan -> rowstart, placement ----------------
// 1024 threads/block (16 waves/CU) — grid is ~1 block/CU, so per-block thread
// parallelism is the latency-hiding lever.
__global__ __launch_bounds__(1024) void bucket_build(const int2* __restrict__ etmp,
                                                     const uint* __restrict__ bbase,
                                                     float* __restrict__ dis,
                                                     int* __restrict__ hist_g,
                                                     int* __restrict__ rowstart,
                                                     int2* __restrict__ edges) {
    __shared__ u64   wc[BSZ];       // (count<<40) | sum(wq23)
    __shared__ uint  cur[BSZ];
    __shared__ float disl[BSZ];
    int tid = threadIdx.x;
    int b = blockIdx.x;
    int n0 = b * BSZ;
    for (int i = tid; i < BSZ; i += 1024) wc[i] = 0ull;
    __syncthreads();
    uint base = bbase[b], end = bbase[b + 1];
    for (uint i = base + tid; i < end; i += 1024) {
        uint y = (uint)etmp[i].y;
        uint dl = y >> 23;
        atomicAdd(&wc[dl], ((u64)1 << 40) | (u64)(y & 0x7fffffu));
    }
    __syncthreads();
    // exclusive scan of counts in wave 0 (chunk of 7 per lane; 7*64=448>=400)
    if (tid < 64) {
        uint v[7], s = 0;
#pragma unroll
        for (int k = 0; k < 7; ++k) {
            int i = tid * 7 + k;
            v[k] = (i < BSZ) ? (uint)(wc[i] >> 40) : 0u;
            s += v[k];
        }
        uint inc = s;
#pragma unroll
        for (int d = 1; d < 64; d <<= 1) {
            uint t = __shfl_up(inc, (unsigned)d, 64);
            if (tid >= d) inc += t;
        }
        uint run = inc - s;
#pragma unroll
        for (int k = 0; k < 7; ++k) {
            int i = tid * 7 + k;
            if (i < BSZ) { cur[i] = run; run += v[k]; }
        }
    }
    __syncthreads();
    // per-node outputs (rowstart snapshot BEFORE placement mutates cur)
    for (int i = tid; i < BSZ; i += 1024) {
        u64 v = wc[i];
        float wsum = (float)(v & 0xffffffffffull) * (1.0f / 8388608.0f);
        float ds = rsqrtf(1.0f + wsum);
        disl[i] = ds;
        dis[n0 + i] = ds;
        hist_g[n0 + i] = (int)(v >> 40);
        rowstart[n0 + i] = (int)(base + cur[i]);
    }
    __syncthreads();
    // placement into block-exclusive region [base, end)
    for (uint i = base + tid; i < end; i += 1024) {
        int2 e = etmp[i];
        uint y = (uint)e.y;
        uint dl = y >> 23;
        float wv = (float)(y & 0x7fffffu) * (1.0f / 8388608.0f);
        uint p = atomicAdd(&cur[dl], 1u);
        float nrm = wv * disl[dl];
        edges[base + p] = make_int2(e.x, __float_as_int(nrm));
    }
}

// ---------------- MFMA GEMM: HB[r,:] = bf16( (X[r,:] @ W) * dis[r] ) ----------------
// W pre-converted/transposed (bf16 [n][k]); staging is a pure vectorized short8
// copy into padded LDS (WTS=136 -> 16B-aligned ds_read_b128, <=2-way bank
// aliasing = free). Layouts (m89/m91): A: m=lane&15, k=(lane>>4)*8+j;
// B: n=lane&15, same k; D: col=lane&15, row=(lane>>4)*4+reg.
#define WTS 136
#define NTILES ((NN + 63) / 64)

template <bool AF32>
__global__ __launch_bounds__(256) void gemm_mfma(const void* __restrict__ Xv,
                                                 const ushort* __restrict__ Wtg,
                                                 const float* __restrict__ dis,
                                                 ushort* __restrict__ HB) {
    __shared__ ushort Wt[DD * WTS];        // 34 KB
    int tid = threadIdx.x;
    // 128 rows x 16 chunks of 8 ushorts = 2048 units; 8 per thread
#pragma unroll
    for (int u = 0; u < 8; ++u) {
        int unit = tid + u * 256;
        int n = unit >> 4, c = unit & 15;
        short8 v = *(const short8*)(Wtg + n * DD + c * 8);
        *(short8*)&Wt[n * WTS + c * 8] = v;
    }
    __syncthreads();

    int wave = tid >> 6, lane = tid & 63;
    int q = lane >> 4, l16 = lane & 15;

    for (int tile = blockIdx.x; tile < NTILES; tile += gridDim.x) {
        int row0 = tile * 64 + wave * 16;

        int arow = row0 + l16;
        if (arow >= NN) arow = NN - 1;
        short8 afr[4];
        if (AF32) {
            const float* xr = (const float*)Xv + (size_t)arow * DD + q * 8;
#pragma unroll
            for (int ks = 0; ks < 4; ++ks) {
                float4 f0 = *(const float4*)(xr + ks * 32);
                float4 f1 = *(const float4*)(xr + ks * 32 + 4);
                uint4 u;
                u.x = f2bf(f0.x) | (f2bf(f0.y) << 16);
                u.y = f2bf(f0.z) | (f2bf(f0.w) << 16);
                u.z = f2bf(f1.x) | (f2bf(f1.y) << 16);
                u.w = f2bf(f1.z) | (f2bf(f1.w) << 16);
                afr[ks] = __builtin_bit_cast(short8, u);
            }
        } else {
            const ushort* xr = (const ushort*)Xv + (size_t)arow * DD + q * 8;
#pragma unroll
            for (int ks = 0; ks < 4; ++ks)
                afr[ks] = *(const short8*)(xr + ks * 32);
        }

        floatx4 acc[8];
#pragma unroll
        for (int ct = 0; ct < 8; ++ct) acc[ct] = (floatx4)(0.0f);

#pragma unroll
        for (int ct = 0; ct < 8; ++ct) {
            const ushort* wp = &Wt[(ct * 16 + l16) * WTS + q * 8];
#pragma unroll
            for (int ks = 0; ks < 4; ++ks) {
                short8 bfr = *(const short8*)(wp + ks * 32);
                acc[ct] = __builtin_amdgcn_mfma_f32_16x16x32_bf16(afr[ks], bfr, acc[ct], 0, 0, 0);
            }
        }

#pragma unroll
        for (int reg = 0; reg < 4; ++reg) {
            int r = row0 + q * 4 + reg;
            if (r < NN) {
                float ds = dis[r];
                ushort* orow = HB + (size_t)r * DD + l16;
#pragma unroll
                for (int ct = 0; ct < 8; ++ct)
                    orow[ct * 16] = (ushort)f2bf(acc[ct][reg] * ds);
            }
        }
    }
}

// ---------------- fused gather + self-loop + bias + PReLU ----------------
// Wave-per-node: 64 lanes = 128 channels (2 per lane, one uint gather / lane).
// Edge records at wave-uniform addresses -> scalar loads (no readlane).
// Per edge: 1 addr op + 1 gather + 2 unpack + 2 fmac. Chunks of 16 keep >=16
// gathers in flight; one predicated tail chunk (dead src clamped to row 0,
// norm 0). Overread past edge-list end (<=120 B) lands in adjacent hb region.
// [R1-measured: 68.2 us, VGPR 28, 3.72 TB/s — pinned at random-256B L2-miss BW;
//  R2 (scalar, same depth) and R3 (2-node, 32-deep) both ~69-70 -> BW floor.]
template <bool BF16OUT>
__global__ __launch_bounds__(256) void gather_finalize(const ushort* __restrict__ hb,
                                                       const int2* __restrict__ edges,
                                                       const int* __restrict__ rowstart,
                                                       const int* __restrict__ hist,
                                                       const float* __restrict__ dis,
                                                       const float* __restrict__ b,
                                                       const float* __restrict__ a,
                                                       void* __restrict__ xout) {
    int wid = __builtin_amdgcn_readfirstlane(threadIdx.x >> 6);
    int lane = threadIdx.x & 63;
    int node = blockIdx.x * 4 + wid;          // NN % 4 == 0
    uint lane4 = (uint)lane * 4u;

    int rs  = rowstart[node];                 // uniform address -> scalar load
    int cnt = hist[node];
    float ds = dis[node];
    const int2* ep = edges + rs;
    const char* hbase = (const char*)hb;

    // self term (node's own pre-scaled row * dis[node])
    uint su = *(const uint*)(hbase + ((size_t)(uint)node << 8) + lane4);
    float2 acc0, acc1, acc2, acc3;
    acc0.x = __uint_as_float(su << 16) * ds;
    acc0.y = __uint_as_float(su & 0xffff0000u) * ds;
    acc1 = make_float2(0.f, 0.f);
    acc2 = make_float2(0.f, 0.f);
    acc3 = make_float2(0.f, 0.f);

    int full = cnt >> 4;                      // full chunks of 16
    int t = 0;
    for (; t < full; ++t) {
        int2 e[16];
#pragma unroll
        for (int k = 0; k < 16; ++k) e[k] = ep[t * 16 + k];
#pragma unroll
        for (int k = 0; k < 16; ++k) {
            uint voff = ((uint)e[k].x << 8) + lane4;
            uint g = *(const uint*)(hbase + (size_t)voff);
            float nrm = __int_as_float(e[k].y);
            float2* ac = (k & 3) == 0 ? &acc0 : (k & 3) == 1 ? &acc1 : (k & 3) == 2 ? &acc2 : &acc3;
            ac->x += __uint_as_float(g << 16) * nrm;
            ac->y += __uint_as_float(g & 0xffff0000u) * nrm;
        }
    }
    int remn = cnt & 15;
    if (remn) {
        int2 e[16];
#pragma unroll
        for (int k = 0; k < 16; ++k) e[k] = ep[t * 16 + k];   // overread ok
#pragma unroll
        for (int k = 0; k < 16; ++k) {
            bool live = k < remn;                              // uniform
            uint sidx = live ? (uint)e[k].x : 0u;
            float nrm = live ? __int_as_float(e[k].y) : 0.0f;
            uint voff = (sidx << 8) + lane4;
            uint g = *(const uint*)(hbase + (size_t)voff);
            float2* ac = (k & 3) == 0 ? &acc0 : (k & 3) == 1 ? &acc1 : (k & 3) == 2 ? &acc2 : &acc3;
            ac->x += __uint_as_float(g << 16) * nrm;
            ac->y += __uint_as_float(g & 0xffff0000u) * nrm;
        }
    }

    float2 bb = ((const float2*)b)[lane];
    float2 aa = ((const float2*)a)[lane];
    float r0 = acc0.x + acc1.x + acc2.x + acc3.x + bb.x;
    float r1 = acc0.y + acc1.y + acc2.y + acc3.y + bb.y;
    r0 = r0 >= 0.f ? r0 : aa.x * r0;
    r1 = r1 >= 0.f ? r1 : aa.y * r1;
    if (BF16OUT) {
        ((uint*)xout)[(size_t)node * 64 + lane] = f2bf(r0) | (f2bf(r1) << 16);
    } else {
        float2 o; o.x = r0; o.y = r1;
        ((float2*)xout)[(size_t)node * 64 + lane] = o;
    }
}

extern "C" void kernel_launch(void* const* d_in, const int* in_sizes, int n_in,
                              void* d_out, int out_size, void* d_ws, size_t ws_size,
                              hipStream_t stream) {
    const float* feat = (const float*)d_in[0];
    const int*   ei   = (const int*)d_in[1];     // [2, NE]
    const float* ew   = (const float*)d_in[2];
    const float* W1   = (const float*)d_in[3];
    const float* b1   = (const float*)d_in[4];
    const float* a1   = (const float*)d_in[5];
    const float* W2   = (const float*)d_in[6];
    const float* b2   = (const float*)d_in[7];
    const float* a2   = (const float*)d_in[8];
    float* out = (float*)d_out;

    const int* srcp = ei;
    const int* dstp = ei + NE;

    // workspace carve (bytes), all 16B-aligned
    char* wsb = (char*)d_ws;
    size_t off = 0;
    uint* bcp    = (uint*)(wsb + off); off += 262144;               // NB*NHB partials
    ushort* wt1  = (ushort*)(wsb + off); off += 2ull * DD * DD;     // 32 KB
    ushort* wt2  = (ushort*)(wsb + off); off += 2ull * DD * DD;     // 32 KB
    uint* bbase  = (uint*)(wsb + off); off += 4096;                 // NB+1
    uint* bcur   = (uint*)(wsb + off); off += 4096;                 // NB
    float* dis   = (float*)(wsb + off); off += 4ull * NN;           // NN
    int* hist    = (int*)(wsb + off); off += 4ull * NN;             // NN
    int* rowstart= (int*)(wsb + off); off += 4ull * NN;             // NN
    int2* etmp   = (int2*)(wsb + off); off += 8ull * NE;            // NE
    int2* edges  = (int2*)(wsb + off); off += 8ull * NE;            // NE (followed by hb: chunk overread safe)
    ushort* hb   = (ushort*)(wsb + off); off += 2ull * NN * DD;     // NN*DD bf16
    ushort* x1b  = (ushort*)(wsb + off); off += 2ull * NN * DD;     // NN*DD bf16

    // ---- CSR build (bucketed counting sort), weight prep fused into pass 1 ----
    bucket_hist<<<NHB, 256, 0, stream>>>(dstp, bcp, W1, W2, wt1, wt2);
    bucket_prefix<<<1, 256, 0, stream>>>(bcp, bbase, bcur);
    bucket_append<<<(NE + 4095) / 4096, 256, 0, stream>>>(srcp, dstp, ew, bcur, etmp);
    bucket_build<<<NB, 1024, 0, stream>>>(etmp, bbase, dis, hist, rowstart, edges);

    const int gemm_blocks = (NTILES + 1) / 2;   // 2 tiles/block
    const int gath_blocks = NN / 4;             // wave per node

    // ---- layer 1 ----
    gemm_mfma<true><<<gemm_blocks, 256, 0, stream>>>(feat, wt1, dis, hb);
    gather_finalize<true><<<gath_blocks, 256, 0, stream>>>(hb, edges, rowstart, hist, dis, b1, a1, x1b);
    // ---- layer 2 ----
    gemm_mfma<false><<<gemm_blocks, 256, 0, stream>>>(x1b, wt2, dis, hb);
    gather_finalize<false><<<gath_blocks, 256, 0, stream>>>(hb, edges, rowstart, hist, dis, b2, a2, out);
}